// Round 1
// baseline (175.937 us; speedup 1.0000x reference)
//
#include <hip/hip_runtime.h>

#define N_NODES_C 50000
#define K_NEIGH 16
#define IN_DIM 128
#define OUT_DIM 128
#define TWO_D 256

#define BM 64              // nodes per block
#define LSTRIDE 260        // LDS row stride in floats (1040 B, 16B-aligned)

__global__ __launch_bounds__(256, 2)
void sage_fused(const int* __restrict__ nodes,
                const float* __restrict__ embs,
                const int* __restrict__ neigh,
                const float* __restrict__ W,
                float* __restrict__ out,
                int n_nodes)
{
    __shared__ float comb[BM * LSTRIDE];
    const int tid = threadIdx.x;
    const int block_n0 = blockIdx.x * BM;

    // ---------------- Phase 1: gather self + mean(neighbors) into LDS ----------------
    // group g = tid/32 handles nodes g*8 .. g*8+7; lane l = tid%32 covers floats [4l, 4l+4)
    {
        const int g = tid >> 5;
        const int l = tid & 31;
        #pragma unroll
        for (int s = 0; s < 8; ++s) {
            const int nloc = g * 8 + s;
            const int n = block_n0 + nloc;
            if (n >= n_nodes) break;

            // self features -> cols [0, 128)
            const int self_row = nodes[n];
            const float4 sv = *reinterpret_cast<const float4*>(
                embs + (size_t)self_row * IN_DIM + 4 * l);
            *reinterpret_cast<float4*>(&comb[nloc * LSTRIDE + 4 * l]) = sv;

            // mean of 16 neighbors -> cols [128, 256)
            float4 acc = make_float4(0.f, 0.f, 0.f, 0.f);
            const int* nidx = neigh + (size_t)n * K_NEIGH;
            #pragma unroll
            for (int k = 0; k < K_NEIGH; ++k) {
                const int r = nidx[k];
                const float4 v = *reinterpret_cast<const float4*>(
                    embs + (size_t)r * IN_DIM + 4 * l);
                acc.x += v.x; acc.y += v.y; acc.z += v.z; acc.w += v.w;
            }
            const float inv = 1.0f / (float)K_NEIGH;
            acc.x *= inv; acc.y *= inv; acc.z *= inv; acc.w *= inv;
            *reinterpret_cast<float4*>(&comb[nloc * LSTRIDE + IN_DIM + 4 * l]) = acc;
        }
    }
    __syncthreads();

    // ---------------- Phase 2: out[n][o] = relu(sum_k comb[n][k] * W[o][k]) ----------
    // thread: oc = tid%32 -> outputs [oc*4, oc*4+4); ng = tid/32 -> nodes ng*8..+7
    {
        const int oc = tid & 31;
        const int ng = tid >> 5;
        float acc[8][4];
        #pragma unroll
        for (int i = 0; i < 8; ++i)
            #pragma unroll
            for (int j = 0; j < 4; ++j) acc[i][j] = 0.f;

        for (int k = 0; k < TWO_D; k += 4) {
            float4 w[4];
            #pragma unroll
            for (int j = 0; j < 4; ++j)
                w[j] = *reinterpret_cast<const float4*>(
                    W + (size_t)(oc * 4 + j) * TWO_D + k);
            #pragma unroll
            for (int i = 0; i < 8; ++i) {
                const float4 c = *reinterpret_cast<const float4*>(
                    &comb[(ng * 8 + i) * LSTRIDE + k]);
                #pragma unroll
                for (int j = 0; j < 4; ++j) {
                    acc[i][j] += c.x * w[j].x;
                    acc[i][j] += c.y * w[j].y;
                    acc[i][j] += c.z * w[j].z;
                    acc[i][j] += c.w * w[j].w;
                }
            }
        }

        #pragma unroll
        for (int i = 0; i < 8; ++i) {
            const int n = block_n0 + ng * 8 + i;
            if (n < n_nodes) {
                float4 o4;
                o4.x = fmaxf(acc[i][0], 0.f);
                o4.y = fmaxf(acc[i][1], 0.f);
                o4.z = fmaxf(acc[i][2], 0.f);
                o4.w = fmaxf(acc[i][3], 0.f);
                *reinterpret_cast<float4*>(out + (size_t)n * OUT_DIM + oc * 4) = o4;
            }
        }
    }
}

extern "C" void kernel_launch(void* const* d_in, const int* in_sizes, int n_in,
                              void* d_out, int out_size, void* d_ws, size_t ws_size,
                              hipStream_t stream) {
    const int*   nodes = (const int*)d_in[0];
    const float* embs  = (const float*)d_in[1];
    const int*   neigh = (const int*)d_in[2];
    const float* W     = (const float*)d_in[3];
    float* out = (float*)d_out;

    const int n_nodes = in_sizes[0];           // 50000
    const int grid = (n_nodes + BM - 1) / BM;  // 782

    sage_fused<<<grid, 256, 0, stream>>>(nodes, embs, neigh, W, out, n_nodes);
}

// Round 2
// 87.276 us; speedup vs baseline: 2.0159x; 2.0159x over previous
//
#include <hip/hip_runtime.h>

#define K_NEIGH 16
#define IN_DIM 128
#define OUT_DIM 128
#define TWO_D 256

#define BM 32          // nodes per block
#define LSTR 264       // ushort elems per LDS row (528 B = 33*16 -> b128-aligned, low conflict)

typedef __attribute__((ext_vector_type(8))) short bf16x8;
typedef __attribute__((ext_vector_type(4))) float f32x4;

__device__ __forceinline__ unsigned short f2bf(float x) {
    union { float f; unsigned u; } v; v.f = x;
    unsigned r = v.u + 0x7fffu + ((v.u >> 16) & 1u);   // RNE
    return (unsigned short)(r >> 16);
}

// Convert W[128][256] fp32 -> MFMA B-fragment-ordered bf16 in workspace.
// frag[((nt*8 + ks)*64 + lane)*8 + j] = bf16( W[nt*16 + (lane&15)][ks*32 + (lane>>4)*8 + j] )
__global__ void prep_wfrag(const float* __restrict__ W, unsigned short* __restrict__ frag) {
    const int t = blockIdx.x * 256 + threadIdx.x;
    if (t >= 8 * 8 * 64) return;
    const int lane = t & 63;
    const int ks = (t >> 6) & 7;
    const int nt = t >> 9;
    const int n  = nt * 16 + (lane & 15);
    const int k0 = ks * 32 + (lane >> 4) * 8;
    const float* src = W + (size_t)n * TWO_D + k0;
    const float4 a = *reinterpret_cast<const float4*>(src);
    const float4 b = *reinterpret_cast<const float4*>(src + 4);
    ushort4 lo = { f2bf(a.x), f2bf(a.y), f2bf(a.z), f2bf(a.w) };
    ushort4 hi = { f2bf(b.x), f2bf(b.y), f2bf(b.z), f2bf(b.w) };
    unsigned short* dst = frag + (size_t)t * 8;
    *reinterpret_cast<ushort4*>(dst)     = lo;
    *reinterpret_cast<ushort4*>(dst + 4) = hi;
}

__global__ __launch_bounds__(256, 5)
void sage_fused(const int* __restrict__ nodes,
                const float* __restrict__ embs,
                const int* __restrict__ neigh,
                const unsigned short* __restrict__ wfrag,
                float* __restrict__ out,
                int n_nodes)
{
    __shared__ unsigned short comb[BM * LSTR];   // bf16 combined [self | mean(neigh)]
    const int tid = threadIdx.x;
    const int block_n0 = blockIdx.x * BM;

    // ---------- Phase 1: gather self + mean(16 neighbors), fp32 accum -> bf16 LDS ----------
    // group g = tid/32 handles nodes g*4..g*4+3; lane l covers floats [4l, 4l+4)
    {
        const int g = tid >> 5;
        const int l = tid & 31;
        for (int s = 0; s < 4; ++s) {
            const int nloc = g * 4 + s;
            const int n = block_n0 + nloc;
            unsigned short* row = &comb[nloc * LSTR];
            if (n < n_nodes) {
                const int self_row = nodes[n];
                const float4 sv = *reinterpret_cast<const float4*>(
                    embs + (size_t)self_row * IN_DIM + 4 * l);
                ushort4 s4 = { f2bf(sv.x), f2bf(sv.y), f2bf(sv.z), f2bf(sv.w) };
                *reinterpret_cast<ushort4*>(row + 4 * l) = s4;

                float ax = 0.f, ay = 0.f, az = 0.f, aw = 0.f;
                const int* nidx = neigh + (size_t)n * K_NEIGH;
                #pragma unroll
                for (int k = 0; k < K_NEIGH; ++k) {
                    const float4 v = *reinterpret_cast<const float4*>(
                        embs + (size_t)nidx[k] * IN_DIM + 4 * l);
                    ax += v.x; ay += v.y; az += v.z; aw += v.w;
                }
                const float inv = 0.0625f;
                ushort4 m4 = { f2bf(ax * inv), f2bf(ay * inv), f2bf(az * inv), f2bf(aw * inv) };
                *reinterpret_cast<ushort4*>(row + IN_DIM + 4 * l) = m4;
            } else {
                ushort4 z = { 0, 0, 0, 0 };
                *reinterpret_cast<ushort4*>(row + 4 * l) = z;
                *reinterpret_cast<ushort4*>(row + IN_DIM + 4 * l) = z;
            }
        }
    }
    __syncthreads();

    // ---------- Phase 2: MFMA GEMM  out[m][n] = relu(sum_k comb[m][k] * W[n][k]) ----------
    // 4 waves; wave w: m-tile = w&1, n-tiles = (w>>1)*4 .. +3. K = 256 in 8 steps of 32.
    {
        const int wave = tid >> 6;
        const int lane = tid & 63;
        const int m  = wave & 1;
        const int nq = (wave >> 1) * 4;
        const int row16 = lane & 15;
        const int hi    = lane >> 4;

        f32x4 acc0 = {0,0,0,0}, acc1 = {0,0,0,0}, acc2 = {0,0,0,0}, acc3 = {0,0,0,0};

        // A fragment: lane holds comb[m*16 + (lane&15)][ks*32 + (lane>>4)*8 + j], j=0..7
        const unsigned short* arow = &comb[(m * 16 + row16) * LSTR + hi * 8];
        const unsigned short* bbase = wfrag + ((size_t)nq * 8 * 64 + (size_t)lane) * 8;

        #pragma unroll
        for (int ks = 0; ks < 8; ++ks) {
            const bf16x8 a = *reinterpret_cast<const bf16x8*>(arow + ks * 32);
            const bf16x8 b0 = *reinterpret_cast<const bf16x8*>(bbase + (size_t)(0 * 8 + ks) * 64 * 8);
            const bf16x8 b1 = *reinterpret_cast<const bf16x8*>(bbase + (size_t)(1 * 8 + ks) * 64 * 8);
            const bf16x8 b2 = *reinterpret_cast<const bf16x8*>(bbase + (size_t)(2 * 8 + ks) * 64 * 8);
            const bf16x8 b3 = *reinterpret_cast<const bf16x8*>(bbase + (size_t)(3 * 8 + ks) * 64 * 8);
            acc0 = __builtin_amdgcn_mfma_f32_16x16x32_bf16(a, b0, acc0, 0, 0, 0);
            acc1 = __builtin_amdgcn_mfma_f32_16x16x32_bf16(a, b1, acc1, 0, 0, 0);
            acc2 = __builtin_amdgcn_mfma_f32_16x16x32_bf16(a, b2, acc2, 0, 0, 0);
            acc3 = __builtin_amdgcn_mfma_f32_16x16x32_bf16(a, b3, acc3, 0, 0, 0);
        }

        // C/D: col = lane&15 (n), row = (lane>>4)*4 + reg (m)  [m89-verified]
        #define STORE_TILE(J, ACC)                                              \
        {                                                                       \
            const int ncol = (nq + (J)) * 16 + row16;                           \
            _Pragma("unroll")                                                   \
            for (int r = 0; r < 4; ++r) {                                       \
                const int mrow = m * 16 + hi * 4 + r;                           \
                const int n = block_n0 + mrow;                                  \
                if (n < n_nodes)                                                \
                    out[(size_t)n * OUT_DIM + ncol] = fmaxf((ACC)[r], 0.f);     \
            }                                                                   \
        }
        STORE_TILE(0, acc0)
        STORE_TILE(1, acc1)
        STORE_TILE(2, acc2)
        STORE_TILE(3, acc3)
        #undef STORE_TILE
    }
}

extern "C" void kernel_launch(void* const* d_in, const int* in_sizes, int n_in,
                              void* d_out, int out_size, void* d_ws, size_t ws_size,
                              hipStream_t stream) {
    const int*   nodes = (const int*)d_in[0];
    const float* embs  = (const float*)d_in[1];
    const int*   neigh = (const int*)d_in[2];
    const float* W     = (const float*)d_in[3];
    float* out = (float*)d_out;
    unsigned short* wfrag = (unsigned short*)d_ws;   // 64 KiB of fragment-ordered bf16 W

    const int n_nodes = in_sizes[0];                  // 50000

    prep_wfrag<<<16, 256, 0, stream>>>(W, wfrag);

    const int grid = (n_nodes + BM - 1) / BM;         // 1563
    sage_fused<<<grid, 256, 0, stream>>>(nodes, embs, neigh, wfrag, out, n_nodes);
}

// Round 3
// 58.386 us; speedup vs baseline: 3.0134x; 1.4948x over previous
//
#include <hip/hip_runtime.h>

#define K_NEIGH 16
#define IN_DIM 128
#define OUT_DIM 128
#define TWO_D 256

#define BM 32          // nodes per block
#define LSTR 264       // ushort elems per LDS comb row (528 B); == 132 floats for out staging

typedef __attribute__((ext_vector_type(8))) short bf16x8;
typedef __attribute__((ext_vector_type(8))) unsigned short u16x8;
typedef __attribute__((ext_vector_type(4))) float f32x4;

__device__ __forceinline__ unsigned short f2bf(float x) {
    union { float f; unsigned u; } v; v.f = x;
    unsigned r = v.u + 0x7fffu + ((v.u >> 16) & 1u);   // RNE
    return (unsigned short)(r >> 16);
}
__device__ __forceinline__ float bf2f(unsigned short x) {
    union { unsigned u; float f; } v; v.u = ((unsigned)x) << 16;
    return v.f;
}

// ---- embs fp32 [100000][128] -> bf16 table in ws ----
__global__ void conv_embs(const float* __restrict__ embs, unsigned short* __restrict__ btab,
                          int total4) {
    int i = blockIdx.x * blockDim.x + threadIdx.x;
    const int stride = gridDim.x * blockDim.x;
    for (; i < total4; i += stride) {
        const float4 v = reinterpret_cast<const float4*>(embs)[i];
        ushort4 o = { f2bf(v.x), f2bf(v.y), f2bf(v.z), f2bf(v.w) };
        reinterpret_cast<ushort4*>(btab)[i] = o;
    }
}

// ---- W[128][256] fp32 -> MFMA B-fragment-ordered bf16 (same layout as R2, verified) ----
// frag[((nt*8 + ks)*64 + lane)*8 + j] = bf16( W[nt*16 + (lane&15)][ks*32 + (lane>>4)*8 + j] )
__global__ void prep_wfrag(const float* __restrict__ W, unsigned short* __restrict__ frag) {
    const int t = blockIdx.x * 256 + threadIdx.x;
    if (t >= 8 * 8 * 64) return;
    const int lane = t & 63;
    const int ks = (t >> 6) & 7;
    const int nt = t >> 9;
    const int n  = nt * 16 + (lane & 15);
    const int k0 = ks * 32 + (lane >> 4) * 8;
    const float* src = W + (size_t)n * TWO_D + k0;
    const float4 a = *reinterpret_cast<const float4*>(src);
    const float4 b = *reinterpret_cast<const float4*>(src + 4);
    ushort4 lo = { f2bf(a.x), f2bf(a.y), f2bf(a.z), f2bf(a.w) };
    ushort4 hi = { f2bf(b.x), f2bf(b.y), f2bf(b.z), f2bf(b.w) };
    unsigned short* dst = frag + (size_t)t * 8;
    *reinterpret_cast<ushort4*>(dst)     = lo;
    *reinterpret_cast<ushort4*>(dst + 4) = hi;
}

template <int BF16TAB>
__global__ __launch_bounds__(256, 6)
void sage_fused(const int* __restrict__ nodes,
                const float* __restrict__ embs,
                const unsigned short* __restrict__ btab,
                const int* __restrict__ neigh,
                const unsigned short* __restrict__ wfrag,
                float* __restrict__ out,
                int n_nodes)
{
    __shared__ unsigned short comb[BM * LSTR];   // bf16 combined; reused as fp32 out staging
    __shared__ int sidx[BM];
    __shared__ int nb[BM * K_NEIGH];

    const int tid = threadIdx.x;
    const int block_n0 = blockIdx.x * BM;
    const int nvalid = min(BM, n_nodes - block_n0);

    // ---------- Phase 0: stage indices in LDS (coalesced) ----------
    if (tid < BM)
        sidx[tid] = (tid < nvalid) ? nodes[block_n0 + tid] : 0;
    {
        const int nv16 = nvalid * K_NEIGH;
        for (int i = tid; i < BM * K_NEIGH; i += 256)
            nb[i] = (i < nv16) ? neigh[(size_t)block_n0 * K_NEIGH + i] : 0;
    }
    __syncthreads();

    // ---------- Phase 1: gather self + mean(16 neighbors) -> bf16 comb ----------
    // 16 groups of 16 lanes; group g handles nodes g*2, g*2+1; lane covers 16 B of row
    {
        const int g = tid >> 4;
        const int l = tid & 15;
        #pragma unroll
        for (int s = 0; s < 2; ++s) {
            const int nloc = g * 2 + s;
            unsigned short* row = &comb[nloc * LSTR];
            if (nloc < nvalid) {
                float ax[8];
                #pragma unroll
                for (int j = 0; j < 8; ++j) ax[j] = 0.f;

                if (BF16TAB) {
                    const u16x8 sv = *reinterpret_cast<const u16x8*>(
                        btab + (size_t)sidx[nloc] * IN_DIM + 8 * l);
                    *reinterpret_cast<u16x8*>(row + 8 * l) = sv;
                    #pragma unroll
                    for (int k = 0; k < K_NEIGH; ++k) {
                        const u16x8 v = *reinterpret_cast<const u16x8*>(
                            btab + (size_t)nb[nloc * K_NEIGH + k] * IN_DIM + 8 * l);
                        #pragma unroll
                        for (int j = 0; j < 8; ++j) ax[j] += bf2f((unsigned short)v[j]);
                    }
                } else {
                    const float* srow = embs + (size_t)sidx[nloc] * IN_DIM + 8 * l;
                    const float4 s0 = *reinterpret_cast<const float4*>(srow);
                    const float4 s1 = *reinterpret_cast<const float4*>(srow + 4);
                    ushort4 t0 = { f2bf(s0.x), f2bf(s0.y), f2bf(s0.z), f2bf(s0.w) };
                    ushort4 t1 = { f2bf(s1.x), f2bf(s1.y), f2bf(s1.z), f2bf(s1.w) };
                    *reinterpret_cast<ushort4*>(row + 8 * l)     = t0;
                    *reinterpret_cast<ushort4*>(row + 8 * l + 4) = t1;
                    #pragma unroll
                    for (int k = 0; k < K_NEIGH; ++k) {
                        const float* nrow = embs + (size_t)nb[nloc * K_NEIGH + k] * IN_DIM + 8 * l;
                        const float4 v0 = *reinterpret_cast<const float4*>(nrow);
                        const float4 v1 = *reinterpret_cast<const float4*>(nrow + 4);
                        ax[0] += v0.x; ax[1] += v0.y; ax[2] += v0.z; ax[3] += v0.w;
                        ax[4] += v1.x; ax[5] += v1.y; ax[6] += v1.z; ax[7] += v1.w;
                    }
                }
                const float inv = 0.0625f;
                u16x8 m8;
                #pragma unroll
                for (int j = 0; j < 8; ++j) m8[j] = f2bf(ax[j] * inv);
                *reinterpret_cast<u16x8*>(row + IN_DIM + 8 * l) = m8;
            } else {
                u16x8 z = { 0, 0, 0, 0, 0, 0, 0, 0 };
                *reinterpret_cast<u16x8*>(row + 8 * l) = z;
                *reinterpret_cast<u16x8*>(row + IN_DIM + 8 * l) = z;
            }
        }
    }
    __syncthreads();

    // ---------- Phase 2: MFMA GEMM ----------
    const int wave = tid >> 6;
    const int lane = tid & 63;
    const int m  = wave & 1;
    const int nq = (wave >> 1) * 4;
    const int row16 = lane & 15;
    const int hi    = lane >> 4;

    f32x4 acc0 = {0,0,0,0}, acc1 = {0,0,0,0}, acc2 = {0,0,0,0}, acc3 = {0,0,0,0};
    {
        const unsigned short* arow = &comb[(m * 16 + row16) * LSTR + hi * 8];
        const unsigned short* bbase = wfrag + ((size_t)nq * 8 * 64 + (size_t)lane) * 8;
        #pragma unroll
        for (int ks = 0; ks < 8; ++ks) {
            const bf16x8 a = *reinterpret_cast<const bf16x8*>(arow + ks * 32);
            const bf16x8 b0 = *reinterpret_cast<const bf16x8*>(bbase + (size_t)(0 * 8 + ks) * 64 * 8);
            const bf16x8 b1 = *reinterpret_cast<const bf16x8*>(bbase + (size_t)(1 * 8 + ks) * 64 * 8);
            const bf16x8 b2 = *reinterpret_cast<const bf16x8*>(bbase + (size_t)(2 * 8 + ks) * 64 * 8);
            const bf16x8 b3 = *reinterpret_cast<const bf16x8*>(bbase + (size_t)(3 * 8 + ks) * 64 * 8);
            acc0 = __builtin_amdgcn_mfma_f32_16x16x32_bf16(a, b0, acc0, 0, 0, 0);
            acc1 = __builtin_amdgcn_mfma_f32_16x16x32_bf16(a, b1, acc1, 0, 0, 0);
            acc2 = __builtin_amdgcn_mfma_f32_16x16x32_bf16(a, b2, acc2, 0, 0, 0);
            acc3 = __builtin_amdgcn_mfma_f32_16x16x32_bf16(a, b3, acc3, 0, 0, 0);
        }
    }
    __syncthreads();   // all A-fragment reads of comb are done

    // ---------- Phase 3: stage relu(acc) in LDS (stride 132), coalesced store ----------
    {
        float* otile = reinterpret_cast<float*>(comb);   // [32][132]
        #define PUT_TILE(J, ACC)                                                \
        {                                                                       \
            const int ncol = (nq + (J)) * 16 + row16;                           \
            _Pragma("unroll")                                                   \
            for (int r = 0; r < 4; ++r) {                                       \
                const int mrow = m * 16 + hi * 4 + r;                           \
                otile[mrow * 132 + ncol] = fmaxf((ACC)[r], 0.f);                \
            }                                                                   \
        }
        PUT_TILE(0, acc0)
        PUT_TILE(1, acc1)
        PUT_TILE(2, acc2)
        PUT_TILE(3, acc3)
        #undef PUT_TILE
        __syncthreads();

        const int rrow = tid >> 3;       // 0..31
        const int seg  = tid & 7;        // 16 floats each
        if (rrow < nvalid) {
            const float* src = otile + rrow * 132 + seg * 16;
            float4* dst = reinterpret_cast<float4*>(
                out + (size_t)(block_n0 + rrow) * OUT_DIM + seg * 16);
            #pragma unroll
            for (int j = 0; j < 4; ++j)
                dst[j] = reinterpret_cast<const float4*>(src)[j];
        }
    }
}

extern "C" void kernel_launch(void* const* d_in, const int* in_sizes, int n_in,
                              void* d_out, int out_size, void* d_ws, size_t ws_size,
                              hipStream_t stream) {
    const int*   nodes = (const int*)d_in[0];
    const float* embs  = (const float*)d_in[1];
    const int*   neigh = (const int*)d_in[2];
    const float* W     = (const float*)d_in[3];
    float* out = (float*)d_out;

    const int n_nodes = in_sizes[0];                     // 50000
    const int n_unique = in_sizes[1] / IN_DIM;           // 100000
    const size_t btab_elems = (size_t)n_unique * IN_DIM; // 12.8M ushorts = 25.6 MB
    const size_t wfrag_elems = 8 * 8 * 64 * 8;           // 64 KiB
    const bool use_btab = ws_size >= (btab_elems + wfrag_elems) * sizeof(unsigned short);

    unsigned short* base = (unsigned short*)d_ws;
    unsigned short* btab  = base;
    unsigned short* wfrag = use_btab ? (base + btab_elems) : base;

    prep_wfrag<<<16, 256, 0, stream>>>(W, wfrag);

    const int grid = (n_nodes + BM - 1) / BM;            // 1563
    if (use_btab) {
        const int total4 = (int)(btab_elems / 4);
        conv_embs<<<2048, 256, 0, stream>>>(embs, btab, total4);
        sage_fused<1><<<grid, 256, 0, stream>>>(nodes, embs, btab, neigh, wfrag, out, n_nodes);
    } else {
        sage_fused<0><<<grid, 256, 0, stream>>>(nodes, embs, btab, neigh, wfrag, out, n_nodes);
    }
}

// Round 4
// 55.627 us; speedup vs baseline: 3.1628x; 1.0496x over previous
//
#include <hip/hip_runtime.h>

#define K_NEIGH 16
#define IN_DIM 128
#define OUT_DIM 128
#define TWO_D 256

#define BM 16          // nodes per block (50000 % 16 == 0 -> no tail)
#define LSTR 264       // ushort elems per LDS comb row (528 B); == 132 floats for out staging

typedef __attribute__((ext_vector_type(8))) short bf16x8;
typedef __attribute__((ext_vector_type(8))) unsigned short u16x8;
typedef __attribute__((ext_vector_type(4))) float f32x4;

__device__ __forceinline__ unsigned short f2bf(float x) {
    union { float f; unsigned u; } v; v.f = x;
    unsigned r = v.u + 0x7fffu + ((v.u >> 16) & 1u);   // RNE
    return (unsigned short)(r >> 16);
}
__device__ __forceinline__ float bf2f(unsigned short x) {
    union { unsigned u; float f; } v; v.u = ((unsigned)x) << 16;
    return v.f;
}

// ---- embs fp32 [100000][128] -> bf16 table in ws ----
__global__ void conv_embs(const float* __restrict__ embs, unsigned short* __restrict__ btab,
                          int total4) {
    int i = blockIdx.x * blockDim.x + threadIdx.x;
    const int stride = gridDim.x * blockDim.x;
    for (; i < total4; i += stride) {
        const float4 v = reinterpret_cast<const float4*>(embs)[i];
        ushort4 o = { f2bf(v.x), f2bf(v.y), f2bf(v.z), f2bf(v.w) };
        reinterpret_cast<ushort4*>(btab)[i] = o;
    }
}

// ---- W[128][256] fp32 -> MFMA B-fragment-ordered bf16 (verified layout) ----
// frag[((nt*8 + ks)*64 + lane)*8 + j] = bf16( W[nt*16 + (lane&15)][ks*32 + (lane>>4)*8 + j] )
__global__ void prep_wfrag(const float* __restrict__ W, unsigned short* __restrict__ frag) {
    const int t = blockIdx.x * 256 + threadIdx.x;
    if (t >= 8 * 8 * 64) return;
    const int lane = t & 63;
    const int ks = (t >> 6) & 7;
    const int nt = t >> 9;
    const int n  = nt * 16 + (lane & 15);
    const int k0 = ks * 32 + (lane >> 4) * 8;
    const float* src = W + (size_t)n * TWO_D + k0;
    const float4 a = *reinterpret_cast<const float4*>(src);
    const float4 b = *reinterpret_cast<const float4*>(src + 4);
    ushort4 lo = { f2bf(a.x), f2bf(a.y), f2bf(a.z), f2bf(a.w) };
    ushort4 hi = { f2bf(b.x), f2bf(b.y), f2bf(b.z), f2bf(b.w) };
    unsigned short* dst = frag + (size_t)t * 8;
    *reinterpret_cast<ushort4*>(dst)     = lo;
    *reinterpret_cast<ushort4*>(dst + 4) = hi;
}

template <int BF16TAB>
__global__ __launch_bounds__(256, 4)
void sage_fused(const int* __restrict__ nodes,
                const float* __restrict__ embs,
                const unsigned short* __restrict__ btab,
                const int* __restrict__ neigh,
                const unsigned short* __restrict__ wfrag,
                float* __restrict__ out,
                int n_nodes)
{
    __shared__ unsigned short comb[BM * LSTR];   // bf16 combined; reused as fp32 out staging
    __shared__ int sidx[BM];
    __shared__ int nb[BM * K_NEIGH];

    const int tid = threadIdx.x;
    const int block_n0 = blockIdx.x * BM;
    const int nvalid = min(BM, n_nodes - block_n0);

    // ---------- Phase 0: stage indices in LDS (coalesced) ----------
    if (tid < BM)
        sidx[tid] = (tid < nvalid) ? nodes[block_n0 + tid] : 0;
    {
        const int i = tid;                       // exactly BM*K_NEIGH = 256
        nb[i] = (i < nvalid * K_NEIGH) ? neigh[(size_t)block_n0 * K_NEIGH + i] : 0;
    }
    __syncthreads();

    // ---------- Phase 1: gather self + 16 neighbors fully in-flight, then reduce ----------
    // node = tid>>4 (one per 16 lanes), lane l = tid&15 covers bytes [16l, 16l+16) of the row
    {
        const int nloc = tid >> 4;
        const int l = tid & 15;
        unsigned short* row = &comb[nloc * LSTR];
        if (nloc < nvalid) {
            const int* nptr = &nb[nloc * K_NEIGH];
            if (BF16TAB) {
                const u16x8 sv = *reinterpret_cast<const u16x8*>(
                    btab + (size_t)sidx[nloc] * IN_DIM + 8 * l);
                u16x8 v[K_NEIGH];
                #pragma unroll
                for (int k = 0; k < K_NEIGH; ++k)
                    v[k] = *reinterpret_cast<const u16x8*>(
                        btab + (size_t)nptr[k] * IN_DIM + 8 * l);
                *reinterpret_cast<u16x8*>(row + 8 * l) = sv;
                float ax[8];
                #pragma unroll
                for (int j = 0; j < 8; ++j) ax[j] = 0.f;
                #pragma unroll
                for (int k = 0; k < K_NEIGH; ++k)
                    #pragma unroll
                    for (int j = 0; j < 8; ++j)
                        ax[j] += bf2f((unsigned short)v[k][j]);
                u16x8 m8;
                #pragma unroll
                for (int j = 0; j < 8; ++j) m8[j] = f2bf(ax[j] * 0.0625f);
                *reinterpret_cast<u16x8*>(row + IN_DIM + 8 * l) = m8;
            } else {
                // fp32 fallback: two batches of 8 rows to bound VGPR use
                const float* srow = embs + (size_t)sidx[nloc] * IN_DIM + 8 * l;
                const float4 s0 = *reinterpret_cast<const float4*>(srow);
                const float4 s1 = *reinterpret_cast<const float4*>(srow + 4);
                ushort4 t0 = { f2bf(s0.x), f2bf(s0.y), f2bf(s0.z), f2bf(s0.w) };
                ushort4 t1 = { f2bf(s1.x), f2bf(s1.y), f2bf(s1.z), f2bf(s1.w) };
                *reinterpret_cast<ushort4*>(row + 8 * l)     = t0;
                *reinterpret_cast<ushort4*>(row + 8 * l + 4) = t1;
                float ax[8];
                #pragma unroll
                for (int j = 0; j < 8; ++j) ax[j] = 0.f;
                #pragma unroll
                for (int b = 0; b < 2; ++b) {
                    float4 v0[8], v1[8];
                    #pragma unroll
                    for (int k = 0; k < 8; ++k) {
                        const float* nrow = embs + (size_t)nptr[b * 8 + k] * IN_DIM + 8 * l;
                        v0[k] = *reinterpret_cast<const float4*>(nrow);
                        v1[k] = *reinterpret_cast<const float4*>(nrow + 4);
                    }
                    #pragma unroll
                    for (int k = 0; k < 8; ++k) {
                        ax[0] += v0[k].x; ax[1] += v0[k].y; ax[2] += v0[k].z; ax[3] += v0[k].w;
                        ax[4] += v1[k].x; ax[5] += v1[k].y; ax[6] += v1[k].z; ax[7] += v1[k].w;
                    }
                }
                u16x8 m8;
                #pragma unroll
                for (int j = 0; j < 8; ++j) m8[j] = f2bf(ax[j] * 0.0625f);
                *reinterpret_cast<u16x8*>(row + IN_DIM + 8 * l) = m8;
            }
        } else {
            u16x8 z = { 0, 0, 0, 0, 0, 0, 0, 0 };
            *reinterpret_cast<u16x8*>(row + 8 * l) = z;
            *reinterpret_cast<u16x8*>(row + IN_DIM + 8 * l) = z;
        }
    }
    __syncthreads();

    // ---------- Phase 2: MFMA GEMM (M-tile = 16, each wave: 2 n-tiles x 8 k-steps) ----------
    const int wave = tid >> 6;
    const int lane = tid & 63;
    const int nq = wave * 2;
    const int row16 = lane & 15;
    const int hi    = lane >> 4;

    f32x4 acc0 = {0,0,0,0}, acc1 = {0,0,0,0};
    {
        const unsigned short* arow = &comb[row16 * LSTR + hi * 8];
        const unsigned short* bbase = wfrag + ((size_t)nq * 8 * 64 + (size_t)lane) * 8;
        #pragma unroll
        for (int ks = 0; ks < 8; ++ks) {
            const bf16x8 a = *reinterpret_cast<const bf16x8*>(arow + ks * 32);
            const bf16x8 b0 = *reinterpret_cast<const bf16x8*>(bbase + (size_t)(0 * 8 + ks) * 64 * 8);
            const bf16x8 b1 = *reinterpret_cast<const bf16x8*>(bbase + (size_t)(1 * 8 + ks) * 64 * 8);
            acc0 = __builtin_amdgcn_mfma_f32_16x16x32_bf16(a, b0, acc0, 0, 0, 0);
            acc1 = __builtin_amdgcn_mfma_f32_16x16x32_bf16(a, b1, acc1, 0, 0, 0);
        }
    }
    __syncthreads();   // all A-fragment reads of comb are done

    // ---------- Phase 3: stage relu(acc) in LDS, coalesced float4 stores ----------
    {
        float* otile = reinterpret_cast<float*>(comb);   // [16][132]
        #define PUT_TILE(J, ACC)                                                \
        {                                                                       \
            const int ncol = (nq + (J)) * 16 + row16;                           \
            _Pragma("unroll")                                                   \
            for (int r = 0; r < 4; ++r) {                                       \
                const int mrow = hi * 4 + r;                                    \
                otile[mrow * 132 + ncol] = fmaxf((ACC)[r], 0.f);                \
            }                                                                   \
        }
        PUT_TILE(0, acc0)
        PUT_TILE(1, acc1)
        #undef PUT_TILE
        __syncthreads();

        const int rrow = tid >> 4;       // 0..15
        const int seg  = tid & 15;       // 8 floats each
        if (rrow < nvalid) {
            const float* src = otile + rrow * 132 + seg * 8;
            float4* dst = reinterpret_cast<float4*>(
                out + (size_t)(block_n0 + rrow) * OUT_DIM + seg * 8);
            dst[0] = reinterpret_cast<const float4*>(src)[0];
            dst[1] = reinterpret_cast<const float4*>(src)[1];
        }
    }
}

extern "C" void kernel_launch(void* const* d_in, const int* in_sizes, int n_in,
                              void* d_out, int out_size, void* d_ws, size_t ws_size,
                              hipStream_t stream) {
    const int*   nodes = (const int*)d_in[0];
    const float* embs  = (const float*)d_in[1];
    const int*   neigh = (const int*)d_in[2];
    const float* W     = (const float*)d_in[3];
    float* out = (float*)d_out;

    const int n_nodes = in_sizes[0];                     // 50000
    const int n_unique = in_sizes[1] / IN_DIM;           // 100000
    const size_t btab_elems = (size_t)n_unique * IN_DIM; // 12.8M ushorts = 25.6 MB
    const size_t wfrag_elems = 8 * 8 * 64 * 8;           // 64 KiB
    const bool use_btab = ws_size >= (btab_elems + wfrag_elems) * sizeof(unsigned short);

    unsigned short* base = (unsigned short*)d_ws;
    unsigned short* btab  = base;
    unsigned short* wfrag = use_btab ? (base + btab_elems) : base;

    prep_wfrag<<<16, 256, 0, stream>>>(W, wfrag);

    const int grid = (n_nodes + BM - 1) / BM;            // 3125
    if (use_btab) {
        const int total4 = (int)(btab_elems / 4);
        conv_embs<<<2048, 256, 0, stream>>>(embs, btab, total4);
        sage_fused<1><<<grid, 256, 0, stream>>>(nodes, embs, btab, neigh, wfrag, out, n_nodes);
    } else {
        sage_fused<0><<<grid, 256, 0, stream>>>(nodes, embs, btab, neigh, wfrag, out, n_nodes);
    }
}

// Round 5
// 52.425 us; speedup vs baseline: 3.3560x; 1.0611x over previous
//
#include <hip/hip_runtime.h>

#define K_NEIGH 16
#define IN_DIM 128
#define OUT_DIM 128
#define TWO_D 256

#define BM 16          // nodes per block (50000 % 16 == 0 -> no tail)
#define LSTR 264       // ushort elems per LDS comb row (528 B); == 132 floats for out staging

typedef __attribute__((ext_vector_type(8))) short bf16x8;
typedef __attribute__((ext_vector_type(4))) unsigned short u16x4;
typedef __attribute__((ext_vector_type(4))) float f32x4;

__device__ __forceinline__ unsigned short f2bf(float x) {
    union { float f; unsigned u; } v; v.f = x;
    unsigned r = v.u + 0x7fffu + ((v.u >> 16) & 1u);   // RNE
    return (unsigned short)(r >> 16);
}
__device__ __forceinline__ float bf2f(unsigned short x) {
    union { unsigned u; float f; } v; v.u = ((unsigned)x) << 16;
    return v.f;
}

// ---- one prep kernel: blocks [0,16) build W-fragments; blocks [16,..) convert embs ----
// wfrag layout (verified R2-R4):
// frag[((nt*8 + ks)*64 + lane)*8 + j] = bf16( W[nt*16 + (lane&15)][ks*32 + (lane>>4)*8 + j] )
__global__ void prep_all(const float* __restrict__ W, const float* __restrict__ embs,
                         unsigned short* __restrict__ wfrag, unsigned short* __restrict__ btab,
                         int total4) {
    const int b = blockIdx.x;
    if (b < 16) {
        const int t = b * 256 + threadIdx.x;          // 0..4095
        const int lane = t & 63;
        const int ks = (t >> 6) & 7;
        const int nt = t >> 9;
        const int n  = nt * 16 + (lane & 15);
        const int k0 = ks * 32 + (lane >> 4) * 8;
        const float* src = W + (size_t)n * TWO_D + k0;
        const float4 a = *reinterpret_cast<const float4*>(src);
        const float4 c = *reinterpret_cast<const float4*>(src + 4);
        ushort4 lo = { f2bf(a.x), f2bf(a.y), f2bf(a.z), f2bf(a.w) };
        ushort4 hi = { f2bf(c.x), f2bf(c.y), f2bf(c.z), f2bf(c.w) };
        unsigned short* dst = wfrag + (size_t)t * 8;
        *reinterpret_cast<ushort4*>(dst)     = lo;
        *reinterpret_cast<ushort4*>(dst + 4) = hi;
    } else {
        int i = (b - 16) * 256 + threadIdx.x;
        const int stride = (gridDim.x - 16) * 256;
        for (; i < total4; i += stride) {
            const float4 v = reinterpret_cast<const float4*>(embs)[i];
            ushort4 o = { f2bf(v.x), f2bf(v.y), f2bf(v.z), f2bf(v.w) };
            reinterpret_cast<ushort4*>(btab)[i] = o;
        }
    }
}

template <int BF16TAB>
__global__ __launch_bounds__(512, 8)
void sage_fused(const int* __restrict__ nodes,
                const float* __restrict__ embs,
                const unsigned short* __restrict__ btab,
                const int* __restrict__ neigh,
                const unsigned short* __restrict__ wfrag,
                float* __restrict__ out,
                int n_nodes)
{
    __shared__ unsigned short comb[BM * LSTR];   // bf16 combined; reused as fp32 out staging
    __shared__ int sidx[BM];
    __shared__ int nb[BM * K_NEIGH];

    const int tid = threadIdx.x;
    const int block_n0 = blockIdx.x * BM;
    const int nvalid = min(BM, n_nodes - block_n0);   // 16 for all blocks (50000%16==0)

    // ---------- Phase 0: stage indices ----------
    if (tid < BM)
        sidx[tid] = (tid < nvalid) ? nodes[block_n0 + tid] : 0;
    if (tid < BM * K_NEIGH)
        nb[tid] = (tid < nvalid * K_NEIGH) ? neigh[(size_t)block_n0 * K_NEIGH + tid] : 0;
    __syncthreads();

    // ---------- Phase 1: gather self + 16 neighbors; 32 lanes/node, 8 B/lane/row ----------
    {
        const int nloc = tid >> 5;        // 0..15
        const int l = tid & 31;           // covers ushorts [4l, 4l+4)
        unsigned short* row = &comb[nloc * LSTR];
        if (nloc < nvalid) {
            const int* nptr = &nb[nloc * K_NEIGH];
            if (BF16TAB) {
                const u16x4 sv = *reinterpret_cast<const u16x4*>(
                    btab + (size_t)sidx[nloc] * IN_DIM + 4 * l);
                u16x4 v[K_NEIGH];
                #pragma unroll
                for (int k = 0; k < K_NEIGH; ++k)
                    v[k] = *reinterpret_cast<const u16x4*>(
                        btab + (size_t)nptr[k] * IN_DIM + 4 * l);
                *reinterpret_cast<u16x4*>(row + 4 * l) = sv;
                float ax[4] = {0.f, 0.f, 0.f, 0.f};
                #pragma unroll
                for (int k = 0; k < K_NEIGH; ++k)
                    #pragma unroll
                    for (int j = 0; j < 4; ++j)
                        ax[j] += bf2f((unsigned short)v[k][j]);
                u16x4 m4;
                #pragma unroll
                for (int j = 0; j < 4; ++j) m4[j] = f2bf(ax[j] * 0.0625f);
                *reinterpret_cast<u16x4*>(row + IN_DIM + 4 * l) = m4;
            } else {
                const float4 sv = *reinterpret_cast<const float4*>(
                    embs + (size_t)sidx[nloc] * IN_DIM + 4 * l);
                ushort4 t4 = { f2bf(sv.x), f2bf(sv.y), f2bf(sv.z), f2bf(sv.w) };
                *reinterpret_cast<ushort4*>(row + 4 * l) = t4;
                float ax[4] = {0.f, 0.f, 0.f, 0.f};
                #pragma unroll
                for (int b2 = 0; b2 < 2; ++b2) {
                    float4 v[8];
                    #pragma unroll
                    for (int k = 0; k < 8; ++k)
                        v[k] = *reinterpret_cast<const float4*>(
                            embs + (size_t)nptr[b2 * 8 + k] * IN_DIM + 4 * l);
                    #pragma unroll
                    for (int k = 0; k < 8; ++k) {
                        ax[0] += v[k].x; ax[1] += v[k].y; ax[2] += v[k].z; ax[3] += v[k].w;
                    }
                }
                u16x4 m4;
                #pragma unroll
                for (int j = 0; j < 4; ++j) m4[j] = f2bf(ax[j] * 0.0625f);
                *reinterpret_cast<u16x4*>(row + IN_DIM + 4 * l) = m4;
            }
        } else {
            u16x4 z = { 0, 0, 0, 0 };
            *reinterpret_cast<u16x4*>(row + 4 * l) = z;
            *reinterpret_cast<u16x4*>(row + IN_DIM + 4 * l) = z;
        }
    }
    __syncthreads();

    // ---------- Phase 2: MFMA GEMM — 8 waves, wave w handles n-tile w, 8 k-steps ----------
    const int wave = tid >> 6;            // 0..7
    const int lane = tid & 63;
    const int row16 = lane & 15;
    const int hi    = lane >> 4;          // 0..3 -> k-base hi*8

    f32x4 acc = {0, 0, 0, 0};
    {
        const unsigned short* arow = &comb[row16 * LSTR + hi * 8];
        const unsigned short* bbase = wfrag + ((size_t)wave * 8 * 64 + (size_t)lane) * 8;
        #pragma unroll
        for (int ks = 0; ks < 8; ++ks) {
            const bf16x8 a = *reinterpret_cast<const bf16x8*>(arow + ks * 32);
            const bf16x8 b = *reinterpret_cast<const bf16x8*>(bbase + (size_t)ks * 64 * 8);
            acc = __builtin_amdgcn_mfma_f32_16x16x32_bf16(a, b, acc, 0, 0, 0);
        }
    }
    __syncthreads();   // comb A-reads done

    // ---------- Phase 3: stage relu(acc) in LDS [16][132], coalesced float4 stores ----------
    {
        float* otile = reinterpret_cast<float*>(comb);
        const int ncol = wave * 16 + row16;
        #pragma unroll
        for (int r = 0; r < 4; ++r)
            otile[(hi * 4 + r) * 132 + ncol] = fmaxf(acc[r], 0.f);
        __syncthreads();

        const int rrow = tid >> 5;        // 0..15
        const int seg  = tid & 31;        // 4 floats each
        if (rrow < nvalid) {
            *reinterpret_cast<float4*>(out + (size_t)(block_n0 + rrow) * OUT_DIM + seg * 4) =
                *reinterpret_cast<const float4*>(otile + rrow * 132 + seg * 4);
        }
    }
}

extern "C" void kernel_launch(void* const* d_in, const int* in_sizes, int n_in,
                              void* d_out, int out_size, void* d_ws, size_t ws_size,
                              hipStream_t stream) {
    const int*   nodes = (const int*)d_in[0];
    const float* embs  = (const float*)d_in[1];
    const int*   neigh = (const int*)d_in[2];
    const float* W     = (const float*)d_in[3];
    float* out = (float*)d_out;

    const int n_nodes = in_sizes[0];                     // 50000
    const int n_unique = in_sizes[1] / IN_DIM;           // 100000
    const size_t btab_elems = (size_t)n_unique * IN_DIM; // 12.8M ushorts = 25.6 MB
    const size_t wfrag_elems = 8 * 8 * 64 * 8;           // 64 KiB
    const bool use_btab = ws_size >= (btab_elems + wfrag_elems) * sizeof(unsigned short);

    unsigned short* base = (unsigned short*)d_ws;
    unsigned short* btab  = base;
    unsigned short* wfrag = use_btab ? (base + btab_elems) : base;

    const int grid = (n_nodes + BM - 1) / BM;            // 3125

    if (use_btab) {
        const int total4 = (int)(btab_elems / 4);
        prep_all<<<16 + 2048, 256, 0, stream>>>(W, embs, wfrag, btab, total4);
        sage_fused<1><<<grid, 512, 0, stream>>>(nodes, embs, btab, neigh, wfrag, out, n_nodes);
    } else {
        prep_all<<<16, 256, 0, stream>>>(W, embs, wfrag, btab, 0);
        sage_fused<0><<<grid, 512, 0, stream>>>(nodes, embs, btab, neigh, wfrag, out, n_nodes);
    }
}

// Round 6
// 40.008 us; speedup vs baseline: 4.3976x; 1.3104x over previous
//
#include <hip/hip_runtime.h>

#define K_NEIGH 16
#define IN_DIM 128
#define OUT_DIM 128
#define TWO_D 256

#define BM 16          // nodes per block (50000 % 16 == 0 -> no tail)
#define LSTR 264       // ushort elems per LDS comb row (528 B); == 132 floats for out staging

typedef __attribute__((ext_vector_type(8))) short bf16x8;
typedef __attribute__((ext_vector_type(4))) unsigned short u16x4;
typedef __attribute__((ext_vector_type(4))) float f32x4;
typedef __attribute__((ext_vector_type(2))) float f32x2;

__device__ __forceinline__ unsigned short f2bf(float x) {
    union { float f; unsigned u; } v; v.f = x;
    unsigned r = v.u + 0x7fffu + ((v.u >> 16) & 1u);   // RNE
    return (unsigned short)(r >> 16);
}

// ---- one prep kernel: blocks [0,16) build W-fragments; blocks [16,..) build fp8 table ----
// wfrag layout (verified R2-R5):
// frag[((nt*8 + ks)*64 + lane)*8 + j] = bf16( W[nt*16 + (lane&15)][ks*32 + (lane>>4)*8 + j] )
__global__ void prep_all(const float* __restrict__ W, const float* __restrict__ embs,
                         unsigned short* __restrict__ wfrag, unsigned* __restrict__ f8tab,
                         int total_ints) {
    const int b = blockIdx.x;
    if (b < 16) {
        const int t = b * 256 + threadIdx.x;          // 0..4095
        const int lane = t & 63;
        const int ks = (t >> 6) & 7;
        const int nt = t >> 9;
        const int n  = nt * 16 + (lane & 15);
        const int k0 = ks * 32 + (lane >> 4) * 8;
        const float* src = W + (size_t)n * TWO_D + k0;
        const float4 a = *reinterpret_cast<const float4*>(src);
        const float4 c = *reinterpret_cast<const float4*>(src + 4);
        ushort4 lo = { f2bf(a.x), f2bf(a.y), f2bf(a.z), f2bf(a.w) };
        ushort4 hi = { f2bf(c.x), f2bf(c.y), f2bf(c.z), f2bf(c.w) };
        unsigned short* dst = wfrag + (size_t)t * 8;
        *reinterpret_cast<ushort4*>(dst)     = lo;
        *reinterpret_cast<ushort4*>(dst + 4) = hi;
    } else {
        // fp8 e4m3 table: one int = 4 fp8 elems, from one float4 of embs
        int i = (b - 16) * 256 + threadIdx.x;
        const int stride = (gridDim.x - 16) * 256;
        for (; i < total_ints; i += stride) {
            const float4 v = reinterpret_cast<const float4*>(embs)[i];
            int p = 0;
            p = __builtin_amdgcn_cvt_pk_fp8_f32(v.x, v.y, p, false);
            p = __builtin_amdgcn_cvt_pk_fp8_f32(v.z, v.w, p, true);
            f8tab[i] = (unsigned)p;
        }
    }
}

template <int USE_F8>
__global__ __launch_bounds__(512, 8)
void sage_fused(const int* __restrict__ nodes,
                const float* __restrict__ embs,
                const unsigned* __restrict__ f8tab,
                const int* __restrict__ neigh,
                const unsigned short* __restrict__ wfrag,
                float* __restrict__ out,
                int n_nodes)
{
    __shared__ unsigned short comb[BM * LSTR];   // bf16 combined; reused as fp32 out staging
    __shared__ int sidx[BM];
    __shared__ int nb[BM * K_NEIGH];

    const int tid = threadIdx.x;
    const int block_n0 = blockIdx.x * BM;
    const int nvalid = min(BM, n_nodes - block_n0);   // 16 for all blocks (50000%16==0)

    // ---------- Phase 0: stage indices ----------
    if (tid < BM)
        sidx[tid] = (tid < nvalid) ? nodes[block_n0 + tid] : 0;
    if (tid < BM * K_NEIGH)
        nb[tid] = (tid < nvalid * K_NEIGH) ? neigh[(size_t)block_n0 * K_NEIGH + tid] : 0;
    __syncthreads();

    // ---------- Phase 1: gather. 32 lanes/node; self fp32 (16 B/lane), neigh fp8 (4 B/lane) --
    {
        const int nloc = tid >> 5;        // 0..15
        const int l = tid & 31;           // elem range [4l, 4l+4)
        unsigned short* row = &comb[nloc * LSTR];
        if (nloc < nvalid) {
            const int* nptr = &nb[nloc * K_NEIGH];
            // self: fp32 direct -> bf16 cols [0,128)
            const float4 sv = *reinterpret_cast<const float4*>(
                embs + (size_t)sidx[nloc] * IN_DIM + 4 * l);
            ushort4 t4 = { f2bf(sv.x), f2bf(sv.y), f2bf(sv.z), f2bf(sv.w) };
            *reinterpret_cast<ushort4*>(row + 4 * l) = t4;

            float ax[4] = {0.f, 0.f, 0.f, 0.f};
            if (USE_F8) {
                unsigned v[K_NEIGH];
                #pragma unroll
                for (int k = 0; k < K_NEIGH; ++k)
                    v[k] = f8tab[(size_t)nptr[k] * (IN_DIM / 4) + l];
                #pragma unroll
                for (int k = 0; k < K_NEIGH; ++k) {
                    const f32x2 lo = __builtin_amdgcn_cvt_pk_f32_fp8((int)v[k], false);
                    const f32x2 hi = __builtin_amdgcn_cvt_pk_f32_fp8((int)v[k], true);
                    ax[0] += lo[0]; ax[1] += lo[1]; ax[2] += hi[0]; ax[3] += hi[1];
                }
            } else {
                #pragma unroll
                for (int b2 = 0; b2 < 2; ++b2) {
                    float4 v[8];
                    #pragma unroll
                    for (int k = 0; k < 8; ++k)
                        v[k] = *reinterpret_cast<const float4*>(
                            embs + (size_t)nptr[b2 * 8 + k] * IN_DIM + 4 * l);
                    #pragma unroll
                    for (int k = 0; k < 8; ++k) {
                        ax[0] += v[k].x; ax[1] += v[k].y; ax[2] += v[k].z; ax[3] += v[k].w;
                    }
                }
            }
            u16x4 m4;
            #pragma unroll
            for (int j = 0; j < 4; ++j) m4[j] = f2bf(ax[j] * 0.0625f);
            *reinterpret_cast<u16x4*>(row + IN_DIM + 4 * l) = m4;
        } else {
            u16x4 z = { 0, 0, 0, 0 };
            *reinterpret_cast<u16x4*>(row + 4 * l) = z;
            *reinterpret_cast<u16x4*>(row + IN_DIM + 4 * l) = z;
        }
    }
    __syncthreads();

    // ---------- Phase 2: MFMA GEMM — 8 waves, wave w handles n-tile w, 8 k-steps ----------
    const int wave = tid >> 6;            // 0..7
    const int lane = tid & 63;
    const int row16 = lane & 15;
    const int hi    = lane >> 4;          // 0..3 -> k-base hi*8

    f32x4 acc = {0, 0, 0, 0};
    {
        const unsigned short* arow = &comb[row16 * LSTR + hi * 8];
        const unsigned short* bbase = wfrag + ((size_t)wave * 8 * 64 + (size_t)lane) * 8;
        #pragma unroll
        for (int ks = 0; ks < 8; ++ks) {
            const bf16x8 a = *reinterpret_cast<const bf16x8*>(arow + ks * 32);
            const bf16x8 b = *reinterpret_cast<const bf16x8*>(bbase + (size_t)ks * 64 * 8);
            acc = __builtin_amdgcn_mfma_f32_16x16x32_bf16(a, b, acc, 0, 0, 0);
        }
    }
    __syncthreads();   // comb A-reads done

    // ---------- Phase 3: stage relu(acc) in LDS [16][132], coalesced float4 stores ----------
    {
        float* otile = reinterpret_cast<float*>(comb);
        const int ncol = wave * 16 + row16;
        #pragma unroll
        for (int r = 0; r < 4; ++r)
            otile[(hi * 4 + r) * 132 + ncol] = fmaxf(acc[r], 0.f);
        __syncthreads();

        const int rrow = tid >> 5;        // 0..15
        const int seg  = tid & 31;        // 4 floats each
        if (rrow < nvalid) {
            *reinterpret_cast<float4*>(out + (size_t)(block_n0 + rrow) * OUT_DIM + seg * 4) =
                *reinterpret_cast<const float4*>(otile + rrow * 132 + seg * 4);
        }
    }
}

extern "C" void kernel_launch(void* const* d_in, const int* in_sizes, int n_in,
                              void* d_out, int out_size, void* d_ws, size_t ws_size,
                              hipStream_t stream) {
    const int*   nodes = (const int*)d_in[0];
    const float* embs  = (const float*)d_in[1];
    const int*   neigh = (const int*)d_in[2];
    const float* W     = (const float*)d_in[3];
    float* out = (float*)d_out;

    const int n_nodes = in_sizes[0];                       // 50000
    const int n_unique = in_sizes[1] / IN_DIM;             // 100000
    const size_t f8tab_bytes = (size_t)n_unique * IN_DIM;  // 12.8 MB (1 B/elem)
    const size_t wfrag_bytes = 8 * 8 * 64 * 8 * 2;         // 64 KiB
    const bool use_f8 = ws_size >= f8tab_bytes + wfrag_bytes;

    unsigned char* base = (unsigned char*)d_ws;
    unsigned* f8tab = (unsigned*)base;
    unsigned short* wfrag = (unsigned short*)(use_f8 ? base + f8tab_bytes : base);

    const int grid = (n_nodes + BM - 1) / BM;              // 3125

    if (use_f8) {
        const int total_ints = (int)(f8tab_bytes / 4);     // 3.2M
        prep_all<<<16 + 2048, 256, 0, stream>>>(W, embs, wfrag, f8tab, total_ints);
        sage_fused<1><<<grid, 512, 0, stream>>>(nodes, embs, f8tab, neigh, wfrag, out, n_nodes);
    } else {
        prep_all<<<16, 256, 0, stream>>>(W, embs, wfrag, f8tab, 0);
        sage_fused<0><<<grid, 512, 0, stream>>>(nodes, embs, f8tab, neigh, wfrag, out, n_nodes);
    }
}